// Round 8
// baseline (53.157 us; speedup 1.0000x reference)
//
#include <hip/hip_runtime.h>
#include <math.h>

#define BS 8
#define N_PTS 8192
#define N_SAMPLES 2048
#define TA 256                    // threads in min kernel (4 waves/block)
#define SPT 8                     // samples per thread: 256*8 = 2048 = full batch
#define PSPLIT 128
#define CHUNK (N_PTS / PSPLIT)    // 64 points per block
#define NSEG 16                   // reduce stage-1 segments (8 pc-rows each)

// ws layout (floats):
//   part[2][BS][PSPLIT][N_SAMPLES]  = 4,194,304 floats (16.8 MB)
//   mid [2][BS][NSEG][N_SAMPLES]    =   524,288 floats (2.1 MB)
//   tsum[16]
#define PART_ELEMS (2 * BS * PSPLIT * N_SAMPLES)
#define MID_ELEMS  (2 * BS * NSEG * N_SAMPLES)

// Kernel A: per (batch, point-chunk) block. Metric per (sample, point):
//   f = |p|^2 - 2 s.p   (monotone in d^2 for fixed s; d^2 = f + |s|^2)
// Cycle model (per CU): VALU ~12us, LDS pipe ~10.2us (524k b128 total, const
// in TA at fixed SPT). R1 had this balance but only 1.4 waves/SIMD -> pipes
// serialized. Here: 1024 blocks x launch_bounds(256,4) = 4 blocks/CU,
// 16 waves/CU -> LDS waits overlap VALU across waves. VGPR cap 128: no spill.
__global__ __launch_bounds__(TA, 4)
void chamfer_min_kernel(const float* __restrict__ gts,
                        const float* __restrict__ preds,
                        const float* __restrict__ grid,
                        float* __restrict__ part)
{
    const int bid = blockIdx.x;
    const int b   = bid >> 7;           // / PSPLIT
    const int pc  = bid & (PSPLIT - 1);
    const int t   = threadIdx.x;

    __shared__ float4 ldsP[CHUNK];
    __shared__ float4 ldsG[CHUNK];

    // Staging: threads 0..63 stage preds chunk, 64..127 stage gts chunk.
    if (t < 2 * CHUNK) {
        const int j = t & (CHUNK - 1);
        const float* src = ((t < CHUNK) ? preds : gts)
                         + ((size_t)b * N_PTS + (size_t)pc * CHUNK + j) * 3;
        const float x = src[0], y = src[1], z = src[2];
        const float4 v = make_float4(x, y, z, fmaf(x, x, fmaf(y, y, z * z)));
        if (t < CHUNK) ldsP[j] = v; else ldsG[j] = v;
    }

    // Per-thread samples (coalesced: s = k*256 + t); ns = -2*s.
    float nsx[SPT], nsy[SPT], nsz[SPT], mP[SPT], mG[SPT];
    {
        const float* grow = grid + (size_t)b * N_SAMPLES * 3;
#pragma unroll
        for (int k = 0; k < SPT; ++k) {
            const int s = k * TA + t;
            nsx[k] = -2.0f * grow[s * 3 + 0];
            nsy[k] = -2.0f * grow[s * 3 + 1];
            nsz[k] = -2.0f * grow[s * 3 + 2];
            mP[k] = 3.0e38f;
            mG[k] = 3.0e38f;
        }
    }

    __syncthreads();

    // Main loop: 2 points per side per iter; 3 fma/pair + min3 shared over 2.
#pragma unroll 4
    for (int j = 0; j < CHUNK; j += 2) {
        const float4 p0 = ldsP[j], p1 = ldsP[j + 1];
        const float4 g0 = ldsG[j], g1 = ldsG[j + 1];
#pragma unroll
        for (int k = 0; k < SPT; ++k) {
            const float x = nsx[k], y = nsy[k], z = nsz[k];
            const float t0 = fmaf(p0.x, x, fmaf(p0.y, y, fmaf(p0.z, z, p0.w)));
            const float t1 = fmaf(p1.x, x, fmaf(p1.y, y, fmaf(p1.z, z, p1.w)));
            mP[k] = fminf(fminf(t0, t1), mP[k]);   // -> v_min3_f32
            const float u0 = fmaf(g0.x, x, fmaf(g0.y, y, fmaf(g0.z, z, g0.w)));
            const float u1 = fmaf(g1.x, x, fmaf(g1.y, y, fmaf(g1.z, z, g1.w)));
            mG[k] = fminf(fminf(u0, u1), mG[k]);
        }
    }

    // Disjoint slices, coalesced dword streaming stores of clamped d^2.
    float* pp = part + (((size_t)b)        * PSPLIT + pc) * N_SAMPLES;
    float* pg = part + (((size_t)(BS + b)) * PSPLIT + pc) * N_SAMPLES;
#pragma unroll
    for (int k = 0; k < SPT; ++k) {
        const int s = k * TA + t;
        const float s2 = 0.25f * fmaf(nsx[k], nsx[k], fmaf(nsy[k], nsy[k], nsz[k] * nsz[k]));
        pp[s] = fmaxf(mP[k] + s2, 0.0f);
        pg[s] = fmaxf(mG[k] + s2, 0.0f);
    }
}

// Kernel B (reduce stage 1): 128 blocks. Block (b, seg) folds 8 of the 128
// pc-rows for all 2048 samples, both sides. float4-vectorized, coalesced.
__global__ __launch_bounds__(256, 1)
void chamfer_red1_kernel(const float* __restrict__ part,
                         float* __restrict__ mid)
{
    const int blk = blockIdx.x;        // 0..127
    const int b   = blk >> 4;
    const int seg = blk & (NSEG - 1);
    const int t   = threadIdx.x;
    const int pc0 = seg * (PSPLIT / NSEG);

    const float4* pp = (const float4*)(part + ((size_t)b        * PSPLIT + pc0) * N_SAMPLES);
    const float4* pg = (const float4*)(part + ((size_t)(BS + b) * PSPLIT + pc0) * N_SAMPLES);
    float4* mp4 = (float4*)(mid + ((size_t)b        * NSEG + seg) * N_SAMPLES);
    float4* mg4 = (float4*)(mid + ((size_t)(BS + b) * NSEG + seg) * N_SAMPLES);

#pragma unroll
    for (int c = 0; c < 2; ++c) {              // 2 float4 columns per thread
        const int g = c * 256 + t;             // 0..511
        float4 mp = make_float4(3.0e38f, 3.0e38f, 3.0e38f, 3.0e38f);
        float4 mg = mp;
#pragma unroll
        for (int r = 0; r < PSPLIT / NSEG; ++r) {
            const float4 a = pp[(size_t)r * (N_SAMPLES / 4) + g];
            mp.x = fminf(mp.x, a.x); mp.y = fminf(mp.y, a.y);
            mp.z = fminf(mp.z, a.z); mp.w = fminf(mp.w, a.w);
            const float4 d = pg[(size_t)r * (N_SAMPLES / 4) + g];
            mg.x = fminf(mg.x, d.x); mg.y = fminf(mg.y, d.y);
            mg.z = fminf(mg.z, d.z); mg.w = fminf(mg.w, d.w);
        }
        mp4[g] = mp;
        mg4[g] = mg;
    }
}

// Kernel C (reduce stage 2): 16 blocks. Block (b, half) folds the 16 segs for
// 1024 samples, applies |sqrt-sqrt|, fixed-tree sums -> tsum[blk].
__global__ __launch_bounds__(256, 1)
void chamfer_red2_kernel(const float* __restrict__ mid,
                         float* __restrict__ tsum)
{
    const int blk  = blockIdx.x;       // 0..15
    const int b    = blk >> 1;
    const int half = blk & 1;
    const int t    = threadIdx.x;

    const float* mp = mid + ((size_t)b        * NSEG) * N_SAMPLES;
    const float* mg = mid + ((size_t)(BS + b) * NSEG) * N_SAMPLES;

    float v = 0.0f;
#pragma unroll
    for (int k = 0; k < 4; ++k) {
        const int s = half * 1024 + k * 256 + t;
        float a = 3.0e38f, c = 3.0e38f;
#pragma unroll
        for (int seg = 0; seg < NSEG; ++seg) {
            a = fminf(a, mp[(size_t)seg * N_SAMPLES + s]);
            c = fminf(c, mg[(size_t)seg * N_SAMPLES + s]);
        }
        v += fabsf(sqrtf(a) - sqrtf(c));
    }

#pragma unroll
    for (int off = 32; off > 0; off >>= 1)
        v += __shfl_down(v, off, 64);

    __shared__ float w[4];
    if ((t & 63) == 0) w[t >> 6] = v;
    __syncthreads();
    if (t == 0) tsum[blk] = (w[0] + w[1]) + (w[2] + w[3]);
}

// Kernel D: combine 2 half sums per batch (fixed order) -> mean.
__global__ __launch_bounds__(64)
void chamfer_out_kernel(const float* __restrict__ tsum,
                        float* __restrict__ out)
{
    const int b = threadIdx.x;
    if (b < BS)
        out[b] = (tsum[2 * b] + tsum[2 * b + 1]) * (1.0f / (float)N_SAMPLES);
}

extern "C" void kernel_launch(void* const* d_in, const int* in_sizes, int n_in,
                              void* d_out, int out_size, void* d_ws, size_t ws_size,
                              hipStream_t stream)
{
    const float* gts   = (const float*)d_in[0];
    const float* preds = (const float*)d_in[1];
    const float* grid  = (const float*)d_in[2];
    float* out  = (float*)d_out;
    float* part = (float*)d_ws;
    float* mid  = part + PART_ELEMS;
    float* tsum = mid + MID_ELEMS;

    chamfer_min_kernel<<<dim3(BS * PSPLIT), dim3(TA), 0, stream>>>(gts, preds, grid, part);
    chamfer_red1_kernel<<<dim3(BS * NSEG), dim3(256), 0, stream>>>(part, mid);
    chamfer_red2_kernel<<<dim3(16), dim3(256), 0, stream>>>(mid, tsum);
    chamfer_out_kernel<<<dim3(1), dim3(64), 0, stream>>>(tsum, out);
}

// Round 9
// 35.710 us; speedup vs baseline: 1.4886x; 1.4886x over previous
//
#include <hip/hip_runtime.h>
#include <math.h>

#define BS 8
#define N_PTS 8192
#define N_SAMPLES 2048
#define THREADS 256
#define SPT 8                    // samples per thread: 256*8 = 2048 = full batch per block
#define PSPLIT 128
#define CHUNK (N_PTS / PSPLIT)   // 64 points per block

// Kernel 1: per (batch, point-chunk) block. Candidate metric per pair:
//   f = |p|^2 - 2 s.p   (monotone in d^2 for fixed s; d^2 = f + |s|^2)
// -> 3 fma + min3(shared over 2 points) = 3.5 VALU ops per pair.
// |s|^2 added + clamped >=0 AFTER the per-thread min, so the uint-bit
// atomicMin sees only non-negative floats (order-preserving, deterministic).
//
// R9 change vs R1 (the 34.25us best): PSPLIT 64->128 => 1024 blocks =
// 4 blocks/CU = 4 waves/SIMD (R1 ran 1.4 waves/SIMD, so its balanced
// LDS-pipe (10.2us/CU) and VALU (12.2us/CU) serialized instead of
// overlapping). NO launch_bounds min-waves arg: no VGPR cap, no spill.
__global__ __launch_bounds__(THREADS, 1)
void chamfer_min_kernel(const float* __restrict__ gts,
                        const float* __restrict__ preds,
                        const float* __restrict__ grid,
                        unsigned int* __restrict__ wsmin) // [2][BS][N_SAMPLES]
{
    const int bid = blockIdx.x;
    const int b   = bid >> 7;            // / PSPLIT
    const int pc  = bid & (PSPLIT - 1);
    const int t   = threadIdx.x;

    __shared__ float4 ldsP[CHUNK];   // {px, py, pz, |p|^2}
    __shared__ float4 ldsG[CHUNK];

    // Staging: threads 0..63 stage preds chunk, 64..127 stage gts chunk.
    if (t < 2 * CHUNK) {
        const int j = t & (CHUNK - 1);
        const float* src = ((t < CHUNK) ? preds : gts)
                         + ((size_t)b * N_PTS + (size_t)pc * CHUNK + j) * 3;
        const float x = src[0], y = src[1], z = src[2];
        const float4 v = make_float4(x, y, z, fmaf(x, x, fmaf(y, y, z * z)));
        if (t < CHUNK) ldsP[j] = v; else ldsG[j] = v;
    }

    // Per-thread samples: ns = -2*s (|s|^2 recovered in epilogue from ns)
    float nsx[SPT], nsy[SPT], nsz[SPT], mP[SPT], mG[SPT];
    {
        const float* grow = grid + (size_t)b * N_SAMPLES * 3;
#pragma unroll
        for (int k = 0; k < SPT; ++k) {
            const int s = k * THREADS + t;
            nsx[k] = -2.0f * grow[s * 3 + 0];
            nsy[k] = -2.0f * grow[s * 3 + 1];
            nsz[k] = -2.0f * grow[s * 3 + 2];
            mP[k] = 3.0e38f;
            mG[k] = 3.0e38f;
        }
    }

    __syncthreads();

    // Main loop: 2 points per side per iter; 3 fma/pair + min3 shared over 2.
#pragma unroll 2
    for (int j = 0; j < CHUNK; j += 2) {
        const float4 p0 = ldsP[j], p1 = ldsP[j + 1];
        const float4 g0 = ldsG[j], g1 = ldsG[j + 1];
#pragma unroll
        for (int k = 0; k < SPT; ++k) {
            const float x = nsx[k], y = nsy[k], z = nsz[k];
            const float t0 = fmaf(p0.x, x, fmaf(p0.y, y, fmaf(p0.z, z, p0.w)));
            const float t1 = fmaf(p1.x, x, fmaf(p1.y, y, fmaf(p1.z, z, p1.w)));
            mP[k] = fminf(fminf(t0, t1), mP[k]);   // -> v_min3_f32
            const float u0 = fmaf(g0.x, x, fmaf(g0.y, y, fmaf(g0.z, z, g0.w)));
            const float u1 = fmaf(g1.x, x, fmaf(g1.y, y, fmaf(g1.z, z, g1.w)));
            mG[k] = fminf(fminf(u0, u1), mG[k]);
        }
    }

    unsigned int* wp = wsmin + (size_t)b * N_SAMPLES;
    unsigned int* wg = wsmin + (size_t)(BS + b) * N_SAMPLES;
#pragma unroll
    for (int k = 0; k < SPT; ++k) {
        const int s = k * THREADS + t;
        const float s2 = 0.25f * fmaf(nsx[k], nsx[k], fmaf(nsy[k], nsy[k], nsz[k] * nsz[k]));
        atomicMin(&wp[s], __float_as_uint(fmaxf(mP[k] + s2, 0.0f)));
        atomicMin(&wg[s], __float_as_uint(fmaxf(mG[k] + s2, 0.0f)));
    }
}

// Kernel 2: per batch, |sqrt(minP2) - sqrt(minG2)| mean over samples.
__global__ __launch_bounds__(THREADS)
void chamfer_finish_kernel(const unsigned int* __restrict__ wsmin,
                           float* __restrict__ out)
{
    const int b = blockIdx.x;
    const int t = threadIdx.x;
    const unsigned int* wp = wsmin + (size_t)b * N_SAMPLES;
    const unsigned int* wg = wsmin + (size_t)(BS + b) * N_SAMPLES;

    float sum = 0.0f;
#pragma unroll
    for (int s = t; s < N_SAMPLES; s += THREADS) {
        const float dp = sqrtf(__uint_as_float(wp[s]));
        const float dg = sqrtf(__uint_as_float(wg[s]));
        sum += fabsf(dp - dg);
    }

    // wave (64-lane) reduction, fixed tree -> deterministic
#pragma unroll
    for (int off = 32; off > 0; off >>= 1)
        sum += __shfl_down(sum, off, 64);

    __shared__ float wsum[THREADS / 64];
    const int wid = t >> 6;
    if ((t & 63) == 0) wsum[wid] = sum;
    __syncthreads();
    if (t == 0) {
        float tot = 0.0f;
#pragma unroll
        for (int w = 0; w < THREADS / 64; ++w) tot += wsum[w];
        out[b] = tot / (float)N_SAMPLES;
    }
}

extern "C" void kernel_launch(void* const* d_in, const int* in_sizes, int n_in,
                              void* d_out, int out_size, void* d_ws, size_t ws_size,
                              hipStream_t stream)
{
    const float* gts   = (const float*)d_in[0];
    const float* preds = (const float*)d_in[1];
    const float* grid  = (const float*)d_in[2];
    float* out = (float*)d_out;
    unsigned int* wsmin = (unsigned int*)d_ws;

    const size_t wsbytes = (size_t)2 * BS * N_SAMPLES * sizeof(unsigned int); // 128 KiB
    // 0x7F7F7F7F as float = 3.39e38 -> acts as +inf for min of clamped metric
    hipMemsetAsync(d_ws, 0x7F, wsbytes, stream);

    chamfer_min_kernel<<<dim3(BS * PSPLIT), dim3(THREADS), 0, stream>>>(gts, preds, grid, wsmin);
    chamfer_finish_kernel<<<dim3(BS), dim3(THREADS), 0, stream>>>(wsmin, out);
}

// Round 10
// 34.278 us; speedup vs baseline: 1.5508x; 1.0418x over previous
//
#include <hip/hip_runtime.h>
#include <math.h>

#define BS 8
#define N_PTS 8192
#define N_SAMPLES 2048

// ---- ws layout (element offsets) ----
// apack: [2][BS][256 strips][64 lanes] float4   (4 MiB)  f16 A-fragments
// bpack: [BS][64 tiles][64 lanes] float4        (512 KiB) f16 B-fragments
// s2f:   [BS][N_SAMPLES] float                  (64 KiB)
// wsmin: [2][BS][N_SAMPLES] uint                (128 KiB) encoded running min
#define APACK_F4 (2 * BS * 256 * 64)        // 262144 float4
#define BPACK_F4 (BS * 64 * 64)             // 32768 float4
#define S2_F     (BS * N_SAMPLES)           // 16384 float
#define WSMIN_U  (2 * BS * N_SAMPLES)       // 32768 uint

typedef float f32x16 __attribute__((ext_vector_type(16)));
typedef _Float16 half8 __attribute__((ext_vector_type(8)));

union H8 { _Float16 h[8]; float4 f4; };

// Order-preserving map float -> uint (monotone for ALL finite floats).
__device__ inline unsigned encf(float x) {
    unsigned u = __float_as_uint(x);
    return (u & 0x80000000u) ? ~u : (u | 0x80000000u);
}
__device__ inline float decf(unsigned u) {
    unsigned b = (u & 0x80000000u) ? (u ^ 0x80000000u) : ~u;
    return __uint_as_float(b);
}

// Prep: build MFMA fragments.
// A (points, M=32 rows/strip): lane l holds row l&31, k=(l>>5)*8+j.
//   K slots: [ph_x,ph_y,ph_z, ph_x,ph_y,ph_z, pl_x,pl_y | pl_z, hp_h, hp_l, 0..]
// B (samples, N=32 cols/tile): lane l holds col l&31, k=(l>>5)*8+j.
//   K slots: [nh_x,nh_y,nh_z, nl_x,nl_y,nl_z, nh_x,nh_y | nh_z, 1, 1, 0..]
// => D[m][n] = ph.nsh + ph.nsl + pl.nsh + |p|^2  ~=  |p|^2 - 2 s.p   (f16 hi/lo split)
__global__ __launch_bounds__(256)
void chamfer_prep_kernel(const float* __restrict__ gts,
                         const float* __restrict__ preds,
                         const float* __restrict__ grid,
                         float4* __restrict__ apack,
                         float4* __restrict__ bpack,
                         float* __restrict__ s2f,
                         unsigned* __restrict__ wsmin)
{
    const int tid = blockIdx.x * 256 + threadIdx.x;   // 0..262143

    // ---- A-pack (all threads) ----
    {
        const int sd = tid >> 17;            // 0 = preds, 1 = gts
        const int b  = (tid >> 14) & 7;
        const int st = (tid >> 6) & 255;
        const int l  = tid & 63;
        const int g  = l >> 5;
        const int idx = st * 32 + (l & 31);
        const float* src = sd ? gts : preds;
        const float x = src[((size_t)b * N_PTS + idx) * 3 + 0];
        const float y = src[((size_t)b * N_PTS + idx) * 3 + 1];
        const float z = src[((size_t)b * N_PTS + idx) * 3 + 2];
        const _Float16 hx = (_Float16)x, hy = (_Float16)y, hz = (_Float16)z;
        const _Float16 lx = (_Float16)(x - (float)hx);
        const _Float16 ly = (_Float16)(y - (float)hy);
        const _Float16 lz = (_Float16)(z - (float)hz);
        const float hp = fmaf(x, x, fmaf(y, y, z * z));
        const _Float16 hh = (_Float16)hp;
        const _Float16 hl = (_Float16)(hp - (float)hh);
        H8 u;
        if (g == 0) {
            u.h[0] = hx; u.h[1] = hy; u.h[2] = hz;
            u.h[3] = hx; u.h[4] = hy; u.h[5] = hz;
            u.h[6] = lx; u.h[7] = ly;
        } else {
            u.h[0] = lz; u.h[1] = hh; u.h[2] = hl;
            u.h[3] = (_Float16)0.f; u.h[4] = (_Float16)0.f;
            u.h[5] = (_Float16)0.f; u.h[6] = (_Float16)0.f; u.h[7] = (_Float16)0.f;
        }
        apack[tid] = u.f4;
    }

    // ---- B-pack ----
    if (tid < BPACK_F4) {
        const int b    = tid >> 12;
        const int tile = (tid >> 6) & 63;
        const int l    = tid & 63;
        const int g    = l >> 5;
        const int s    = tile * 32 + (l & 31);
        const float nx = -2.0f * grid[((size_t)b * N_SAMPLES + s) * 3 + 0];
        const float ny = -2.0f * grid[((size_t)b * N_SAMPLES + s) * 3 + 1];
        const float nz = -2.0f * grid[((size_t)b * N_SAMPLES + s) * 3 + 2];
        const _Float16 nhx = (_Float16)nx, nhy = (_Float16)ny, nhz = (_Float16)nz;
        const _Float16 nlx = (_Float16)(nx - (float)nhx);
        const _Float16 nly = (_Float16)(ny - (float)nhy);
        const _Float16 nlz = (_Float16)(nz - (float)nhz);
        H8 u;
        if (g == 0) {
            u.h[0] = nhx; u.h[1] = nhy; u.h[2] = nhz;
            u.h[3] = nlx; u.h[4] = nly; u.h[5] = nlz;
            u.h[6] = nhx; u.h[7] = nhy;
        } else {
            u.h[0] = nhz; u.h[1] = (_Float16)1.0f; u.h[2] = (_Float16)1.0f;
            u.h[3] = (_Float16)0.f; u.h[4] = (_Float16)0.f;
            u.h[5] = (_Float16)0.f; u.h[6] = (_Float16)0.f; u.h[7] = (_Float16)0.f;
        }
        bpack[tid] = u.f4;
    }

    // ---- |s|^2 table ----
    if (tid < S2_F) {
        const int b = tid >> 11;
        const int s = tid & 2047;
        const float x = grid[((size_t)b * N_SAMPLES + s) * 3 + 0];
        const float y = grid[((size_t)b * N_SAMPLES + s) * 3 + 1];
        const float z = grid[((size_t)b * N_SAMPLES + s) * 3 + 2];
        s2f[tid] = fmaf(x, x, fmaf(y, y, z * z));
    }

    // ---- wsmin init (encoded +inf sentinel) ----
    if (tid < WSMIN_U) wsmin[tid] = 0xFFFFFFFFu;
}

__device__ inline float rmin16(const f32x16& v) {
    const float a = fminf(fminf(v[0], v[1]), fminf(v[2], v[3]));
    const float b = fminf(fminf(v[4], v[5]), fminf(v[6], v[7]));
    const float c = fminf(fminf(v[8], v[9]), fminf(v[10], v[11]));
    const float d = fminf(fminf(v[12], v[13]), fminf(v[14], v[15]));
    return fminf(fminf(a, b), fminf(c, d));
}

// Main: block = (batch, side, strip-group-of-8, sample-half). 4 waves; each
// wave owns 2 strips (2 A-frags resident) and sweeps 32 sample-tiles from
// LDS. Per tile: 1 ds_read_b128 + 2 MFMA (32x32x16 f16) + min-tree + LDS
// atomicMin. C layout (HW-verified): col=lane&31, row=(reg&3)+8(reg>>2)+4(lane>>5);
// lanes l and l+32 jointly cover all 32 rows -> one shfl_xor(32) pair-min.
__global__ __launch_bounds__(256, 1)
void chamfer_mfma_kernel(const float4* __restrict__ apack,
                         const float4* __restrict__ bpack,
                         unsigned* __restrict__ wsmin)
{
    __shared__ float4 bstage[2048];       // 32 tiles x 64 lanes (32 KiB)
    __shared__ unsigned minbuf[1024];     // this half's samples (4 KiB)

    const int bid = blockIdx.x;
    const int b   = bid >> 7;
    const int sd  = (bid >> 6) & 1;
    const int grp = (bid >> 1) & 31;
    const int h   = bid & 1;
    const int t   = threadIdx.x;

    // Stage B fragments for this sample-half (coalesced float4 copies).
    const float4* bsrc = bpack + ((size_t)b * 64 + h * 32) * 64;
#pragma unroll
    for (int i = 0; i < 8; ++i) bstage[i * 256 + t] = bsrc[i * 256 + t];
#pragma unroll
    for (int i = 0; i < 4; ++i) minbuf[i * 256 + t] = 0xFFFFFFFFu;
    __syncthreads();

    const int w = t >> 6, l = t & 63;
    const int st0 = grp * 8 + w * 2;
    const float4* abase = apack + (((size_t)sd * BS + b) * 256) * 64;
    union { float4 f4; half8 v; } ra0, ra1, rb;
    ra0.f4 = abase[(size_t)st0 * 64 + l];
    ra1.f4 = abase[(size_t)(st0 + 1) * 64 + l];

    const f32x16 zacc = (f32x16)(0.0f);

#pragma unroll 2
    for (int tt = 0; tt < 32; ++tt) {
        rb.f4 = bstage[tt * 64 + l];
        const f32x16 d0 = __builtin_amdgcn_mfma_f32_32x32x16_f16(ra0.v, rb.v, zacc, 0, 0, 0);
        const f32x16 d1 = __builtin_amdgcn_mfma_f32_32x32x16_f16(ra1.v, rb.v, zacc, 0, 0, 0);
        float m = fminf(rmin16(d0), rmin16(d1));
        m = fminf(m, __shfl_xor(m, 32, 64));
        if (l < 32) atomicMin(&minbuf[tt * 32 + l], encf(m));
    }

    __syncthreads();
    unsigned* wdst = wsmin + ((size_t)sd * BS + b) * N_SAMPLES + h * 1024;
#pragma unroll
    for (int i = 0; i < 4; ++i) {
        const int ls = i * 256 + t;
        atomicMin(&wdst[ls], minbuf[ls]);
    }
}

// Finish: per batch, d = sqrt(max(f_min + |s|^2, 0)); mean |dP - dG|.
__global__ __launch_bounds__(256)
void chamfer_finish_kernel(const unsigned* __restrict__ wsmin,
                           const float* __restrict__ s2f,
                           float* __restrict__ out)
{
    const int b = blockIdx.x;
    const int t = threadIdx.x;

    float sum = 0.0f;
#pragma unroll
    for (int i = 0; i < 8; ++i) {
        const int s = i * 256 + t;
        const float s2 = s2f[(size_t)b * N_SAMPLES + s];
        const float fp = decf(wsmin[(size_t)b * N_SAMPLES + s]) + s2;
        const float fg = decf(wsmin[((size_t)BS + b) * N_SAMPLES + s]) + s2;
        const float dp = sqrtf(fmaxf(fp, 0.0f));
        const float dg = sqrtf(fmaxf(fg, 0.0f));
        sum += fabsf(dp - dg);
    }

#pragma unroll
    for (int off = 32; off > 0; off >>= 1)
        sum += __shfl_down(sum, off, 64);

    __shared__ float wsum[4];
    if ((t & 63) == 0) wsum[t >> 6] = sum;
    __syncthreads();
    if (t == 0)
        out[b] = ((wsum[0] + wsum[1]) + (wsum[2] + wsum[3])) / (float)N_SAMPLES;
}

extern "C" void kernel_launch(void* const* d_in, const int* in_sizes, int n_in,
                              void* d_out, int out_size, void* d_ws, size_t ws_size,
                              hipStream_t stream)
{
    const float* gts   = (const float*)d_in[0];
    const float* preds = (const float*)d_in[1];
    const float* grid  = (const float*)d_in[2];
    float* out = (float*)d_out;

    float4* apack  = (float4*)d_ws;
    float4* bpack  = apack + APACK_F4;
    float*  s2f    = (float*)(bpack + BPACK_F4);
    unsigned* wsmin = (unsigned*)(s2f + S2_F);

    chamfer_prep_kernel<<<dim3(1024), dim3(256), 0, stream>>>(gts, preds, grid,
                                                              apack, bpack, s2f, wsmin);
    chamfer_mfma_kernel<<<dim3(1024), dim3(256), 0, stream>>>(apack, bpack, wsmin);
    chamfer_finish_kernel<<<dim3(BS), dim3(256), 0, stream>>>(wsmin, s2f, out);
}